// Round 1
// baseline (561.957 us; speedup 1.0000x reference)
//
#include <hip/hip_runtime.h>
#include <math.h>

#define UNITS 512
#define DIN 128

// ws layout (floats):
// [0..511]     colsum   (atomic, zeroed)
// [512..1023]  colsumsq (atomic, zeroed)
// [1024..1535] scale    (written by k2)
// [1536..2047] shift    (written by k2)
// [2048..2559] entropy slots (atomic, zeroed)
#define WS_COLSUM 0
#define WS_COLSQ  512
#define WS_SCALE  1024
#define WS_SHIFT  1536
#define WS_ESLOT  2048
#define N_ESLOT   512

// K1: X = A @ W  (fp32), block tile 64x64, thread tile 4x4, full-K A tile in LDS,
// B staged in two 64-row chunks to stay under LDS limits.
// Also accumulates per-column sum / sumsq partials -> global atomics into ws.
__global__ __launch_bounds__(256) void k1_gemm_stats(
    const float* __restrict__ A, const float* __restrict__ Wm,
    float* __restrict__ X, float* __restrict__ ws)
{
    __shared__ float As[64][132];   // padded stride to break bank conflicts
    __shared__ float Bs[64][64];
    __shared__ float csum[64];
    __shared__ float csq[64];

    const int t  = threadIdx.x;
    const int bx = blockIdx.x & 7;   // 512/64 = 8 col blocks
    const int by = blockIdx.x >> 3;
    const int r0 = by << 6, c0 = bx << 6;

    // stage A tile: 64 rows x 128 cols
#pragma unroll
    for (int i = 0; i < 8; ++i) {
        int flat = (i << 10) + (t << 2);
        int row = flat >> 7, col = flat & 127;
        *(float4*)&As[row][col] = *(const float4*)(A + (size_t)(r0 + row) * DIN + col);
    }
    if (t < 64) { csum[t] = 0.f; csq[t] = 0.f; }

    const int tx = t & 15, ty4 = (t >> 4) << 2;
    float acc[4][4] = {};

    for (int kk = 0; kk < 128; kk += 64) {
        if (kk) __syncthreads();       // protect Bs overwrite
        // stage B chunk: rows kk..kk+64, 64 cols
#pragma unroll
        for (int i = 0; i < 4; ++i) {
            int flat = (i << 10) + (t << 2);
            int row = flat >> 6, col = flat & 63;
            *(float4*)&Bs[row][col] = *(const float4*)(Wm + (size_t)(kk + row) * UNITS + c0 + col);
        }
        __syncthreads();
#pragma unroll 8
        for (int k = 0; k < 64; ++k) {
            float a0 = As[ty4 + 0][kk + k];
            float a1 = As[ty4 + 1][kk + k];
            float a2 = As[ty4 + 2][kk + k];
            float a3 = As[ty4 + 3][kk + k];
            float4 b = *(float4*)&Bs[k][tx << 2];
            acc[0][0] = fmaf(a0, b.x, acc[0][0]);
            acc[0][1] = fmaf(a0, b.y, acc[0][1]);
            acc[0][2] = fmaf(a0, b.z, acc[0][2]);
            acc[0][3] = fmaf(a0, b.w, acc[0][3]);
            acc[1][0] = fmaf(a1, b.x, acc[1][0]);
            acc[1][1] = fmaf(a1, b.y, acc[1][1]);
            acc[1][2] = fmaf(a1, b.z, acc[1][2]);
            acc[1][3] = fmaf(a1, b.w, acc[1][3]);
            acc[2][0] = fmaf(a2, b.x, acc[2][0]);
            acc[2][1] = fmaf(a2, b.y, acc[2][1]);
            acc[2][2] = fmaf(a2, b.z, acc[2][2]);
            acc[2][3] = fmaf(a2, b.w, acc[2][3]);
            acc[3][0] = fmaf(a3, b.x, acc[3][0]);
            acc[3][1] = fmaf(a3, b.y, acc[3][1]);
            acc[3][2] = fmaf(a3, b.z, acc[3][2]);
            acc[3][3] = fmaf(a3, b.w, acc[3][3]);
        }
    }

    // write X tile
#pragma unroll
    for (int i = 0; i < 4; ++i) {
        float4 o = make_float4(acc[i][0], acc[i][1], acc[i][2], acc[i][3]);
        *(float4*)(X + (size_t)(r0 + ty4 + i) * UNITS + c0 + (tx << 2)) = o;
    }

    // per-column partial sums over this block's 64 rows
#pragma unroll
    for (int j = 0; j < 4; ++j) {
        float s = acc[0][j] + acc[1][j] + acc[2][j] + acc[3][j];
        float q = acc[0][j] * acc[0][j] + acc[1][j] * acc[1][j] +
                  acc[2][j] * acc[2][j] + acc[3][j] * acc[3][j];
        atomicAdd(&csum[(tx << 2) + j], s);
        atomicAdd(&csq[(tx << 2) + j], q);
    }
    __syncthreads();
    if (t < 64) {
        atomicAdd(&ws[WS_COLSUM + c0 + t], csum[t]);
        atomicAdd(&ws[WS_COLSQ  + c0 + t], csq[t]);
    }
}

// K2: finalize BN stats -> per-column scale/shift
__global__ void k2_finalize(const float* __restrict__ gamma,
                            const float* __restrict__ beta,
                            float* __restrict__ ws, int Brows)
{
    int c = threadIdx.x;
    float invB = 1.0f / (float)Brows;
    float mean = ws[WS_COLSUM + c] * invB;
    float ex2  = ws[WS_COLSQ  + c] * invB;
    float var  = ex2 - mean * mean;
    float rstd = rsqrtf(var + 1e-3f);
    float sc   = rstd * gamma[c];
    ws[WS_SCALE + c] = sc;
    ws[WS_SHIFT + c] = beta[c] - mean * sc;
}

// K3: z = prior * (x*scale + shift); sparsemax via Newton on the dual;
// entropy accumulation. One row per 64-lane wave, 8 elements per lane.
// In-place: reads x from X (=d_out), writes mask back.
__global__ __launch_bounds__(256) void k3_bn_sparsemax(
    float* __restrict__ X, const float* __restrict__ prior,
    float* __restrict__ ws)
{
    __shared__ float eacc[4];
    const int wave = threadIdx.x >> 6, lane = threadIdx.x & 63;
    const size_t row  = (size_t)blockIdx.x * 4 + wave;
    const size_t base = row * UNITS;
    const int c0 = lane << 2, c1 = 256 + (lane << 2);

    float4 x0 = *(float4*)(X + base + c0);
    float4 x1 = *(float4*)(X + base + c1);
    float4 p0 = *(const float4*)(prior + base + c0);
    float4 p1 = *(const float4*)(prior + base + c1);
    float4 s0 = *(const float4*)(ws + WS_SCALE + c0);
    float4 s1 = *(const float4*)(ws + WS_SCALE + c1);
    float4 h0 = *(const float4*)(ws + WS_SHIFT + c0);
    float4 h1 = *(const float4*)(ws + WS_SHIFT + c1);

    float z[8];
    {
        const float* xa = (const float*)&x0; const float* pa = (const float*)&p0;
        const float* sa = (const float*)&s0; const float* ha = (const float*)&h0;
#pragma unroll
        for (int j = 0; j < 4; ++j) z[j] = pa[j] * fmaf(xa[j], sa[j], ha[j]);
        xa = (const float*)&x1; pa = (const float*)&p1;
        sa = (const float*)&s1; ha = (const float*)&h1;
#pragma unroll
        for (int j = 0; j < 4; ++j) z[4 + j] = pa[j] * fmaf(xa[j], sa[j], ha[j]);
    }

    // wave max
    float m = z[0];
#pragma unroll
    for (int j = 1; j < 8; ++j) m = fmaxf(m, z[j]);
#pragma unroll
    for (int off = 32; off; off >>= 1) m = fmaxf(m, __shfl_xor(m, off, 64));

    // Newton on f(tau) = sum(relu(z - tau)) - 1 (convex, piecewise linear,
    // decreasing). tau0 = max - 1 guarantees f >= 0; iterates increase
    // monotonically and terminate exactly.
    float tau = m - 1.0f;
    for (int it = 0; it < 32; ++it) {
        float S = 0.f, kc = 0.f;
#pragma unroll
        for (int j = 0; j < 8; ++j) {
            if (z[j] > tau) { S += z[j]; kc += 1.f; }
        }
#pragma unroll
        for (int off = 32; off; off >>= 1) {
            S  += __shfl_xor(S, off, 64);
            kc += __shfl_xor(kc, off, 64);
        }
        if (kc < 0.5f) break;           // safety (shouldn't happen)
        float nt = (S - 1.0f) / kc;
        if (!(nt > tau)) break;         // converged (fixed point)
        tau = nt;
    }

    // mask + entropy
    float e = 0.f;
    float4 o0, o1;
    {
        float* of = (float*)&o0;
#pragma unroll
        for (int j = 0; j < 4; ++j) {
            float v = fmaxf(z[j] - tau, 0.f);
            of[j] = v;
            e -= v * logf(v + 1e-15f);
        }
        of = (float*)&o1;
#pragma unroll
        for (int j = 0; j < 4; ++j) {
            float v = fmaxf(z[4 + j] - tau, 0.f);
            of[j] = v;
            e -= v * logf(v + 1e-15f);
        }
    }
    *(float4*)(X + base + c0) = o0;
    *(float4*)(X + base + c1) = o1;

    // entropy: wave reduce -> block reduce -> slotted atomics
#pragma unroll
    for (int off = 32; off; off >>= 1) e += __shfl_xor(e, off, 64);
    if (lane == 0) eacc[wave] = e;
    __syncthreads();
    if (threadIdx.x == 0) {
        float tot = eacc[0] + eacc[1] + eacc[2] + eacc[3];
        atomicAdd(&ws[WS_ESLOT + (blockIdx.x & (N_ESLOT - 1))], tot);
    }
}

// K4: reduce entropy slots -> scalar loss
__global__ void k4_loss(const float* __restrict__ ws, float* __restrict__ out_loss,
                        int Brows)
{
    __shared__ float sh[512];
    int t = threadIdx.x;
    sh[t] = ws[WS_ESLOT + t];
    __syncthreads();
    for (int s = 256; s > 0; s >>= 1) {
        if (t < s) sh[t] += sh[t + s];
        __syncthreads();
    }
    if (t == 0) out_loss[0] = 1e-3f * (sh[0] / (float)Brows) * (1.0f / 3.0f);
}

extern "C" void kernel_launch(void* const* d_in, const int* in_sizes, int n_in,
                              void* d_out, int out_size, void* d_ws, size_t ws_size,
                              hipStream_t stream)
{
    const float* inputs = (const float*)d_in[0];
    const float* prior  = (const float*)d_in[1];
    const float* Wm     = (const float*)d_in[2];
    const float* gamma  = (const float*)d_in[3];
    const float* beta   = (const float*)d_in[4];
    float* out = (float*)d_out;
    float* ws  = (float*)d_ws;
    const int Brows = in_sizes[1] / UNITS;   // 131072

    hipMemsetAsync(ws, 0, (WS_ESLOT + N_ESLOT) * sizeof(float), stream);

    dim3 g1((Brows / 64) * (UNITS / 64));
    k1_gemm_stats<<<g1, 256, 0, stream>>>(inputs, Wm, out, ws);
    k2_finalize<<<1, UNITS, 0, stream>>>(gamma, beta, ws, Brows);
    k3_bn_sparsemax<<<Brows / 4, 256, 0, stream>>>(out, prior, ws);
    k4_loss<<<1, N_ESLOT, 0, stream>>>(ws, out + (size_t)Brows * UNITS, Brows);
}

// Round 2
// 395.741 us; speedup vs baseline: 1.4200x; 1.4200x over previous
//
#include <hip/hip_runtime.h>
#include <math.h>

typedef __attribute__((ext_vector_type(8))) short short8;
typedef __attribute__((ext_vector_type(4))) float f32x4;

#define UNITS 512
#define DIN 128

// ws float layout:
// [0 .. 4095]      colsum, 8 slots x 512 (atomic, zeroed)
// [4096 .. 8191]   colsumsq, 8 slots x 512 (atomic, zeroed)
// [8192 .. 8703]   scale
// [8704 .. 9215]   shift
// [9216 .. 9727]   entropy slots (atomic, zeroed)
// [16384 .. ]      W_hi packed fragments (65536 ushorts = 32768 floats)
// [49152 .. ]      W_lo packed fragments
#define WS_COLSUM 0
#define WS_COLSQ  4096
#define WS_SCALE  8192
#define WS_SHIFT  8704
#define WS_ESLOT  9216
#define N_ESLOT   512
#define WS_WHI    16384
#define WS_WLO    49152

__device__ __forceinline__ unsigned short f2bf(float f) {
    unsigned u = __float_as_uint(f);
    unsigned r = (u + 0x7FFFu + ((u >> 16) & 1u)) >> 16;   // RNE
    return (unsigned short)r;
}
__device__ __forceinline__ float bf2f(unsigned short h) {
    return __uint_as_float(((unsigned)h) << 16);
}

// K0: pack W [128][512] fp32 -> fragment-major bf16 hi/lo.
// Fragment element index for (k, n): c=k>>5, lane=((k>>3)&3)*16 + (n&15),
// j=k&7, t=n>>4  ->  dst = ((c*32+t)*64 + lane)*8 + j
__global__ void k0_packW(const float* __restrict__ W, unsigned short* __restrict__ Whi,
                         unsigned short* __restrict__ Wlo)
{
    int idx = blockIdx.x * 256 + threadIdx.x;   // 0..65535
    int k = idx >> 9, n = idx & 511;
    float v = W[idx];
    int c = k >> 5, j = k & 7, lane = ((k >> 3) & 3) * 16 + (n & 15), t = n >> 4;
    int dst = (((c * 32 + t) * 64 + lane) << 3) + j;
    unsigned short hi = f2bf(v);
    unsigned short lo = f2bf(v - bf2f(hi));
    Whi[dst] = hi;
    Wlo[dst] = lo;
}

// K1: X = A @ W via split-bf16 MFMA. One wave = 16 rows x 512 cols.
// Block = 4 waves = 64 rows. Also accumulates BN col sum/sumsq.
__global__ __launch_bounds__(256) void k1_gemm_stats(
    const float* __restrict__ A, const unsigned short* __restrict__ Whi,
    const unsigned short* __restrict__ Wlo, float* __restrict__ X,
    float* __restrict__ ws)
{
    const int wave = threadIdx.x >> 6, lane = threadIdx.x & 63;
    const int lm = lane & 15, lg = lane >> 4;
    const int r0w = blockIdx.x * 64 + wave * 16;

    // A fragments: lane holds A[r0w+lm][c*32 + lg*8 + j], j=0..7, per chunk c
    short8 ahi[4], alo[4];
    const float* arow = A + (size_t)(r0w + lm) * DIN + lg * 8;
#pragma unroll
    for (int c = 0; c < 4; ++c) {
        float4 f0 = *(const float4*)(arow + c * 32);
        float4 f1 = *(const float4*)(arow + c * 32 + 4);
        float fv[8] = {f0.x, f0.y, f0.z, f0.w, f1.x, f1.y, f1.z, f1.w};
#pragma unroll
        for (int j = 0; j < 8; ++j) {
            unsigned short h = f2bf(fv[j]);
            ahi[c][j] = (short)h;
            alo[c][j] = (short)f2bf(fv[j] - bf2f(h));
        }
    }

    f32x4 acc[32];
#pragma unroll
    for (int t = 0; t < 32; ++t) acc[t] = (f32x4){0.f, 0.f, 0.f, 0.f};

#pragma unroll
    for (int c = 0; c < 4; ++c) {
        const short8* bh = (const short8*)Whi + (c * 32 * 64 + lane);
        const short8* bl = (const short8*)Wlo + (c * 32 * 64 + lane);
#pragma unroll
        for (int t = 0; t < 32; ++t) {
            short8 h = bh[t * 64];
            short8 l = bl[t * 64];
            acc[t] = __builtin_amdgcn_mfma_f32_16x16x32_bf16(alo[c], h, acc[t], 0, 0, 0);
            acc[t] = __builtin_amdgcn_mfma_f32_16x16x32_bf16(ahi[c], l, acc[t], 0, 0, 0);
            acc[t] = __builtin_amdgcn_mfma_f32_16x16x32_bf16(ahi[c], h, acc[t], 0, 0, 0);
        }
    }

    // write X: D row = lg*4+g, col = t*16+lm
    float* xrow = X + (size_t)(r0w + lg * 4) * UNITS + lm;
#pragma unroll
    for (int g = 0; g < 4; ++g) {
#pragma unroll
        for (int t = 0; t < 32; ++t)
            xrow[(size_t)g * UNITS + t * 16] = acc[t][g];
    }

    // BN stats: reduce 16 rows per col (4 regs + 4 lane-groups), slotted atomics
    const int slot = blockIdx.x & 7;
    float* cs = ws + WS_COLSUM + slot * 512;
    float* cq = ws + WS_COLSQ + slot * 512;
#pragma unroll
    for (int t = 0; t < 32; ++t) {
        float s = acc[t][0] + acc[t][1] + acc[t][2] + acc[t][3];
        float q = acc[t][0] * acc[t][0] + acc[t][1] * acc[t][1] +
                  acc[t][2] * acc[t][2] + acc[t][3] * acc[t][3];
        s += __shfl_xor(s, 16, 64); s += __shfl_xor(s, 32, 64);
        q += __shfl_xor(q, 16, 64); q += __shfl_xor(q, 32, 64);
        if (lg == 0) {
            atomicAdd(cs + t * 16 + lm, s);
            atomicAdd(cq + t * 16 + lm, q);
        }
    }
}

// K2: finalize BN stats -> per-column scale/shift
__global__ void k2_finalize(const float* __restrict__ gamma,
                            const float* __restrict__ beta,
                            float* __restrict__ ws, int Brows)
{
    int c = threadIdx.x;
    float s = 0.f, q = 0.f;
    for (int sl = 0; sl < 8; ++sl) {
        s += ws[WS_COLSUM + sl * 512 + c];
        q += ws[WS_COLSQ + sl * 512 + c];
    }
    float invB = 1.0f / (float)Brows;
    float mean = s * invB;
    float var  = q * invB - mean * mean;
    float rstd = rsqrtf(var + 1e-3f);
    float sc   = rstd * gamma[c];
    ws[WS_SCALE + c] = sc;
    ws[WS_SHIFT + c] = beta[c] - mean * sc;
}

// K3: z = prior * (x*scale + shift); sparsemax via Newton on the dual;
// entropy accumulation. One row per 64-lane wave, 8 elements per lane.
__global__ __launch_bounds__(256) void k3_bn_sparsemax(
    float* __restrict__ X, const float* __restrict__ prior,
    float* __restrict__ ws)
{
    __shared__ float eacc[4];
    const int wave = threadIdx.x >> 6, lane = threadIdx.x & 63;
    const size_t row  = (size_t)blockIdx.x * 4 + wave;
    const size_t base = row * UNITS;
    const int c0 = lane << 2, c1 = 256 + (lane << 2);

    float4 x0 = *(float4*)(X + base + c0);
    float4 x1 = *(float4*)(X + base + c1);
    float4 p0 = *(const float4*)(prior + base + c0);
    float4 p1 = *(const float4*)(prior + base + c1);
    float4 s0 = *(const float4*)(ws + WS_SCALE + c0);
    float4 s1 = *(const float4*)(ws + WS_SCALE + c1);
    float4 h0 = *(const float4*)(ws + WS_SHIFT + c0);
    float4 h1 = *(const float4*)(ws + WS_SHIFT + c1);

    float z[8];
    {
        const float* xa = (const float*)&x0; const float* pa = (const float*)&p0;
        const float* sa = (const float*)&s0; const float* ha = (const float*)&h0;
#pragma unroll
        for (int j = 0; j < 4; ++j) z[j] = pa[j] * fmaf(xa[j], sa[j], ha[j]);
        xa = (const float*)&x1; pa = (const float*)&p1;
        sa = (const float*)&s1; ha = (const float*)&h1;
#pragma unroll
        for (int j = 0; j < 4; ++j) z[4 + j] = pa[j] * fmaf(xa[j], sa[j], ha[j]);
    }

    float m = z[0];
#pragma unroll
    for (int j = 1; j < 8; ++j) m = fmaxf(m, z[j]);
#pragma unroll
    for (int off = 32; off; off >>= 1) m = fmaxf(m, __shfl_xor(m, off, 64));

    float tau = m - 1.0f;
    for (int it = 0; it < 32; ++it) {
        float S = 0.f, kc = 0.f;
#pragma unroll
        for (int j = 0; j < 8; ++j) {
            if (z[j] > tau) { S += z[j]; kc += 1.f; }
        }
#pragma unroll
        for (int off = 32; off; off >>= 1) {
            S  += __shfl_xor(S, off, 64);
            kc += __shfl_xor(kc, off, 64);
        }
        if (kc < 0.5f) break;
        float nt = (S - 1.0f) / kc;
        if (!(nt > tau)) break;
        tau = nt;
    }

    float e = 0.f;
    float4 o0, o1;
    {
        float* of = (float*)&o0;
#pragma unroll
        for (int j = 0; j < 4; ++j) {
            float v = fmaxf(z[j] - tau, 0.f);
            of[j] = v;
            e -= v * logf(v + 1e-15f);
        }
        of = (float*)&o1;
#pragma unroll
        for (int j = 0; j < 4; ++j) {
            float v = fmaxf(z[4 + j] - tau, 0.f);
            of[j] = v;
            e -= v * logf(v + 1e-15f);
        }
    }
    *(float4*)(X + base + c0) = o0;
    *(float4*)(X + base + c1) = o1;

#pragma unroll
    for (int off = 32; off; off >>= 1) e += __shfl_xor(e, off, 64);
    if (lane == 0) eacc[wave] = e;
    __syncthreads();
    if (threadIdx.x == 0) {
        float tot = eacc[0] + eacc[1] + eacc[2] + eacc[3];
        atomicAdd(&ws[WS_ESLOT + (blockIdx.x & (N_ESLOT - 1))], tot);
    }
}

// K4: reduce entropy slots -> scalar loss
__global__ void k4_loss(const float* __restrict__ ws, float* __restrict__ out_loss,
                        int Brows)
{
    __shared__ float sh[512];
    int t = threadIdx.x;
    sh[t] = ws[WS_ESLOT + t];
    __syncthreads();
    for (int s = 256; s > 0; s >>= 1) {
        if (t < s) sh[t] += sh[t + s];
        __syncthreads();
    }
    if (t == 0) out_loss[0] = 1e-3f * (sh[0] / (float)Brows) * (1.0f / 3.0f);
}

extern "C" void kernel_launch(void* const* d_in, const int* in_sizes, int n_in,
                              void* d_out, int out_size, void* d_ws, size_t ws_size,
                              hipStream_t stream)
{
    const float* inputs = (const float*)d_in[0];
    const float* prior  = (const float*)d_in[1];
    const float* Wm     = (const float*)d_in[2];
    const float* gamma  = (const float*)d_in[3];
    const float* beta   = (const float*)d_in[4];
    float* out = (float*)d_out;
    float* ws  = (float*)d_ws;
    unsigned short* Whi = (unsigned short*)(ws + WS_WHI);
    unsigned short* Wlo = (unsigned short*)(ws + WS_WLO);
    const int Brows = in_sizes[1] / UNITS;   // 131072

    hipMemsetAsync(ws, 0, (WS_ESLOT + N_ESLOT) * sizeof(float), stream);

    k0_packW<<<256, 256, 0, stream>>>(Wm, Whi, Wlo);
    k1_gemm_stats<<<Brows / 64, 256, 0, stream>>>(inputs, Whi, Wlo, out, ws);
    k2_finalize<<<1, UNITS, 0, stream>>>(gamma, beta, ws, Brows);
    k3_bn_sparsemax<<<Brows / 4, 256, 0, stream>>>(out, prior, ws);
    k4_loss<<<1, N_ESLOT, 0, stream>>>(ws, out + (size_t)Brows * UNITS, Brows);
}

// Round 3
// 325.411 us; speedup vs baseline: 1.7269x; 1.2161x over previous
//
#include <hip/hip_runtime.h>
#include <math.h>

typedef __attribute__((ext_vector_type(8))) short short8;
typedef __attribute__((ext_vector_type(4))) float f32x4;

#define UNITS 512
#define DIN 128

// ws float layout:
// [0 .. 4095]      colsum, 8 slots x 512 (atomic, zeroed)
// [4096 .. 8191]   colsumsq, 8 slots x 512 (atomic, zeroed)
// [8192 .. 8703]   scale
// [8704 .. 9215]   shift
// [9216 .. 9727]   entropy slots (atomic, zeroed)
// [16384 .. ]      W_hi packed fragments (65536 ushorts = 32768 floats)
// [49152 .. ]      W_lo packed fragments
#define WS_COLSUM 0
#define WS_COLSQ  4096
#define WS_SCALE  8192
#define WS_SHIFT  8704
#define WS_ESLOT  9216
#define N_ESLOT   512
#define WS_WHI    16384
#define WS_WLO    49152

__device__ __forceinline__ unsigned short f2bf(float f) {
    unsigned u = __float_as_uint(f);
    unsigned r = (u + 0x7FFFu + ((u >> 16) & 1u)) >> 16;   // RNE
    return (unsigned short)r;
}
__device__ __forceinline__ float bf2f(unsigned short h) {
    return __uint_as_float(((unsigned)h) << 16);
}

// K0: pack W [128][512] fp32 -> fragment-major bf16 hi/lo.
// Fragment element index for (k, n): c=k>>5, lane=((k>>3)&3)*16 + (n&15),
// j=k&7, t=n>>4  ->  dst = ((c*32+t)*64 + lane)*8 + j
__global__ void k0_packW(const float* __restrict__ W, unsigned short* __restrict__ Whi,
                         unsigned short* __restrict__ Wlo)
{
    int idx = blockIdx.x * 256 + threadIdx.x;   // 0..65535
    int k = idx >> 9, n = idx & 511;
    float v = W[idx];
    int c = k >> 5, j = k & 7, lane = ((k >> 3) & 3) * 16 + (n & 15), t = n >> 4;
    int dst = (((c * 32 + t) * 64 + lane) << 3) + j;
    unsigned short hi = f2bf(v);
    unsigned short lo = f2bf(v - bf2f(hi));
    Whi[dst] = hi;
    Wlo[dst] = lo;
}

// K1: X = A @ W via split-bf16 MFMA (3-term).
// One wave = 16 rows x 256 cols (16 tiles, 64 acc VGPRs).
// Block = 4 waves = 32 rows x 512 cols (2 row stripes x 2 col halves).
__global__ __launch_bounds__(256, 3) void k1_gemm_stats(
    const float* __restrict__ A, const unsigned short* __restrict__ Whi,
    const unsigned short* __restrict__ Wlo, float* __restrict__ X,
    float* __restrict__ ws)
{
    const int wave = threadIdx.x >> 6, lane = threadIdx.x & 63;
    const int lm = lane & 15, lg = lane >> 4;
    const int rg = wave >> 1;            // row stripe 0/1
    const int tbase = (wave & 1) << 4;   // col-tile base 0 or 16
    const int r0w = blockIdx.x * 32 + rg * 16;

    // A fragments: lane holds A[r0w+lm][c*32 + lg*8 + j], j=0..7, per chunk c
    short8 ahi[4], alo[4];
    const float* arow = A + (size_t)(r0w + lm) * DIN + lg * 8;
#pragma unroll
    for (int c = 0; c < 4; ++c) {
        float4 f0 = *(const float4*)(arow + c * 32);
        float4 f1 = *(const float4*)(arow + c * 32 + 4);
        float fv[8] = {f0.x, f0.y, f0.z, f0.w, f1.x, f1.y, f1.z, f1.w};
#pragma unroll
        for (int j = 0; j < 8; ++j) {
            unsigned short h = f2bf(fv[j]);
            ahi[c][j] = (short)h;
            alo[c][j] = (short)f2bf(fv[j] - bf2f(h));
        }
    }

    f32x4 acc[16];
#pragma unroll
    for (int t = 0; t < 16; ++t) acc[t] = (f32x4){0.f, 0.f, 0.f, 0.f};

#pragma unroll
    for (int c = 0; c < 4; ++c) {
        const short8* bh = (const short8*)Whi + (c * 32 + tbase) * 64 + lane;
        const short8* bl = (const short8*)Wlo + (c * 32 + tbase) * 64 + lane;
#pragma unroll
        for (int t = 0; t < 16; ++t) {
            short8 h = bh[t * 64];
            short8 l = bl[t * 64];
            acc[t] = __builtin_amdgcn_mfma_f32_16x16x32_bf16(alo[c], h, acc[t], 0, 0, 0);
            acc[t] = __builtin_amdgcn_mfma_f32_16x16x32_bf16(ahi[c], l, acc[t], 0, 0, 0);
            acc[t] = __builtin_amdgcn_mfma_f32_16x16x32_bf16(ahi[c], h, acc[t], 0, 0, 0);
        }
    }

    // write X: D row = lg*4+g, col = (tbase+t)*16+lm
    float* xrow = X + (size_t)(r0w + lg * 4) * UNITS + tbase * 16 + lm;
#pragma unroll
    for (int g = 0; g < 4; ++g) {
#pragma unroll
        for (int t = 0; t < 16; ++t)
            xrow[(size_t)g * UNITS + t * 16] = acc[t][g];
    }

    // BN stats: reduce 16 rows per col (4 regs + 4 lane-groups), slotted atomics
    const int slot = blockIdx.x & 7;
    float* cs = ws + WS_COLSUM + slot * 512 + tbase * 16;
    float* cq = ws + WS_COLSQ + slot * 512 + tbase * 16;
#pragma unroll
    for (int t = 0; t < 16; ++t) {
        float s = acc[t][0] + acc[t][1] + acc[t][2] + acc[t][3];
        float q = acc[t][0] * acc[t][0] + acc[t][1] * acc[t][1] +
                  acc[t][2] * acc[t][2] + acc[t][3] * acc[t][3];
        s += __shfl_xor(s, 16, 64); s += __shfl_xor(s, 32, 64);
        q += __shfl_xor(q, 16, 64); q += __shfl_xor(q, 32, 64);
        if (lg == 0) {
            atomicAdd(cs + t * 16 + lm, s);
            atomicAdd(cq + t * 16 + lm, q);
        }
    }
}

// K2: finalize BN stats -> per-column scale/shift
__global__ void k2_finalize(const float* __restrict__ gamma,
                            const float* __restrict__ beta,
                            float* __restrict__ ws, int Brows)
{
    int c = threadIdx.x;
    float s = 0.f, q = 0.f;
    for (int sl = 0; sl < 8; ++sl) {
        s += ws[WS_COLSUM + sl * 512 + c];
        q += ws[WS_COLSQ + sl * 512 + c];
    }
    float invB = 1.0f / (float)Brows;
    float mean = s * invB;
    float var  = q * invB - mean * mean;
    float rstd = rsqrtf(var + 1e-3f);
    float sc   = rstd * gamma[c];
    ws[WS_SCALE + c] = sc;
    ws[WS_SHIFT + c] = beta[c] - mean * sc;
}

// K3: z = prior * (x*scale + shift); sparsemax via Newton on the dual;
// entropy accumulation. One row per 64-lane wave, 8 elements per lane.
__global__ __launch_bounds__(256) void k3_bn_sparsemax(
    float* __restrict__ X, const float* __restrict__ prior,
    float* __restrict__ ws)
{
    __shared__ float eacc[4];
    const int wave = threadIdx.x >> 6, lane = threadIdx.x & 63;
    const size_t row  = (size_t)blockIdx.x * 4 + wave;
    const size_t base = row * UNITS;
    const int c0 = lane << 2, c1 = 256 + (lane << 2);

    float4 x0 = *(float4*)(X + base + c0);
    float4 x1 = *(float4*)(X + base + c1);
    float4 p0 = *(const float4*)(prior + base + c0);
    float4 p1 = *(const float4*)(prior + base + c1);
    float4 s0 = *(const float4*)(ws + WS_SCALE + c0);
    float4 s1 = *(const float4*)(ws + WS_SCALE + c1);
    float4 h0 = *(const float4*)(ws + WS_SHIFT + c0);
    float4 h1 = *(const float4*)(ws + WS_SHIFT + c1);

    float z[8];
    {
        const float* xa = (const float*)&x0; const float* pa = (const float*)&p0;
        const float* sa = (const float*)&s0; const float* ha = (const float*)&h0;
#pragma unroll
        for (int j = 0; j < 4; ++j) z[j] = pa[j] * fmaf(xa[j], sa[j], ha[j]);
        xa = (const float*)&x1; pa = (const float*)&p1;
        sa = (const float*)&s1; ha = (const float*)&h1;
#pragma unroll
        for (int j = 0; j < 4; ++j) z[4 + j] = pa[j] * fmaf(xa[j], sa[j], ha[j]);
    }

    float m = z[0];
#pragma unroll
    for (int j = 1; j < 8; ++j) m = fmaxf(m, z[j]);
#pragma unroll
    for (int off = 32; off; off >>= 1) m = fmaxf(m, __shfl_xor(m, off, 64));

    float tau = m - 1.0f;
    for (int it = 0; it < 32; ++it) {
        float S = 0.f, kc = 0.f;
#pragma unroll
        for (int j = 0; j < 8; ++j) {
            if (z[j] > tau) { S += z[j]; kc += 1.f; }
        }
#pragma unroll
        for (int off = 32; off; off >>= 1) {
            S  += __shfl_xor(S, off, 64);
            kc += __shfl_xor(kc, off, 64);
        }
        if (kc < 0.5f) break;
        float nt = (S - 1.0f) / kc;
        if (!(nt > tau)) break;
        tau = nt;
    }

    float e = 0.f;
    float4 o0, o1;
    {
        float* of = (float*)&o0;
#pragma unroll
        for (int j = 0; j < 4; ++j) {
            float v = fmaxf(z[j] - tau, 0.f);
            of[j] = v;
            e -= v * logf(v + 1e-15f);
        }
        of = (float*)&o1;
#pragma unroll
        for (int j = 0; j < 4; ++j) {
            float v = fmaxf(z[4 + j] - tau, 0.f);
            of[j] = v;
            e -= v * logf(v + 1e-15f);
        }
    }
    *(float4*)(X + base + c0) = o0;
    *(float4*)(X + base + c1) = o1;

#pragma unroll
    for (int off = 32; off; off >>= 1) e += __shfl_xor(e, off, 64);
    if (lane == 0) eacc[wave] = e;
    __syncthreads();
    if (threadIdx.x == 0) {
        float tot = eacc[0] + eacc[1] + eacc[2] + eacc[3];
        atomicAdd(&ws[WS_ESLOT + (blockIdx.x & (N_ESLOT - 1))], tot);
    }
}

// K4: reduce entropy slots -> scalar loss
__global__ void k4_loss(const float* __restrict__ ws, float* __restrict__ out_loss,
                        int Brows)
{
    __shared__ float sh[512];
    int t = threadIdx.x;
    sh[t] = ws[WS_ESLOT + t];
    __syncthreads();
    for (int s = 256; s > 0; s >>= 1) {
        if (t < s) sh[t] += sh[t + s];
        __syncthreads();
    }
    if (t == 0) out_loss[0] = 1e-3f * (sh[0] / (float)Brows) * (1.0f / 3.0f);
}

extern "C" void kernel_launch(void* const* d_in, const int* in_sizes, int n_in,
                              void* d_out, int out_size, void* d_ws, size_t ws_size,
                              hipStream_t stream)
{
    const float* inputs = (const float*)d_in[0];
    const float* prior  = (const float*)d_in[1];
    const float* Wm     = (const float*)d_in[2];
    const float* gamma  = (const float*)d_in[3];
    const float* beta   = (const float*)d_in[4];
    float* out = (float*)d_out;
    float* ws  = (float*)d_ws;
    unsigned short* Whi = (unsigned short*)(ws + WS_WHI);
    unsigned short* Wlo = (unsigned short*)(ws + WS_WLO);
    const int Brows = in_sizes[1] / UNITS;   // 131072

    hipMemsetAsync(ws, 0, (WS_ESLOT + N_ESLOT) * sizeof(float), stream);

    k0_packW<<<256, 256, 0, stream>>>(Wm, Whi, Wlo);
    k1_gemm_stats<<<Brows / 32, 256, 0, stream>>>(inputs, Whi, Wlo, out, ws);
    k2_finalize<<<1, UNITS, 0, stream>>>(gamma, beta, ws, Brows);
    k3_bn_sparsemax<<<Brows / 4, 256, 0, stream>>>(out, prior, ws);
    k4_loss<<<1, N_ESLOT, 0, stream>>>(ws, out + (size_t)Brows * UNITS, Brows);
}